// Round 11
// baseline (393.418 us; speedup 1.0000x reference)
//
#include <hip/hip_runtime.h>

// Shapes fixed by the reference setup_inputs():
//   x: [B=8, F=512, T=16384] f32 ; out: [8, 16384] f32
#define TT 16384
#define BB 8
#define NB 8       // N_BANDS
#define FB 64      // F / N_BANDS
#define FSPLIT 8   // freq-loop split (grid = 64*4*8 = 2048 blocks)
#define FCHUNK (FB / FSPLIT)   // 8 rows per block

__device__ __forceinline__ float lgf(float g, float x) {
    // log1p(g*x) with g*x in [0,10): 1+g*x in [1,11) -> fast hw log is safe.
    return __logf(fmaf(g, x, 1.0f));
}

// ---------------- Kernel A: log-gamma + depthwise 5-tap diff + ReLU + freq-pool
// 16 outputs/thread via overlapped 20-float register windows: 5 float4 loads
// per row cover [t0-2, t0+18) (neighbors' overlap hits the same cache lines,
// so no extra lines fetched). No LDS, no shuffles, no separate halo loads.
// Edge zero-pad via per-thread shift s in {-2,0,+2} (divergent in 2 waves
// out of 8192). f-loop fully unrolled, depth-1 register prefetch.
__global__ __launch_bounds__(256) void pool_kernel(
    const float* __restrict__ x,
    const float* __restrict__ log_gamma,
    const float* __restrict__ diff_w,   // [8,1,1,5] flat
    const float* __restrict__ diff_b,   // [8]
    float* __restrict__ pool_part)      // [FSPLIT][64][16384]
{
    const int bc = blockIdx.x;                 // b*8 + c
    const int c  = bc & 7;
    const int t0 = blockIdx.y * 4096 + threadIdx.x * 16;
    const int f0 = blockIdx.z * FCHUNK;
    const float* __restrict__ xb = x + ((size_t)bc * FB + f0) * TT;

    const float g  = __expf(log_gamma[c]);
    const float w0 = diff_w[c * 5 + 0], w1 = diff_w[c * 5 + 1],
                w2 = diff_w[c * 5 + 2], w3 = diff_w[c * 5 + 3],
                w4 = diff_w[c * 5 + 4];
    const float bias = diff_b[c];

    // clamped window base: loads always span [b, b+20) within [0, TT]
    const int b = min(max(t0 - 2, 0), TT - 20);
    const int s = t0 - 2 - b;                  // -2 (left edge), 0, +2 (right edge)
    const float* __restrict__ xr = xb + b;

    float acc[16];
    #pragma unroll
    for (int j = 0; j < 16; ++j) acc[j] = 0.f;

    // prime: row 0's 5 loads
    float4 p0 = *reinterpret_cast<const float4*>(xr);
    float4 p1 = *reinterpret_cast<const float4*>(xr + 4);
    float4 p2 = *reinterpret_cast<const float4*>(xr + 8);
    float4 p3 = *reinterpret_cast<const float4*>(xr + 12);
    float4 p4 = *reinterpret_cast<const float4*>(xr + 16);

    #pragma unroll
    for (int f = 0; f < FCHUNK; ++f) {
        const float4 c0 = p0, c1 = p1, c2 = p2, c3 = p3, c4 = p4;
        // prefetch next row (clamped to last row; stays in-bounds)
        const float* __restrict__ nr = xr + (size_t)((f + 1 < FCHUNK) ? f + 1 : f) * TT;
        p0 = *reinterpret_cast<const float4*>(nr);
        p1 = *reinterpret_cast<const float4*>(nr + 4);
        p2 = *reinterpret_cast<const float4*>(nr + 8);
        p3 = *reinterpret_cast<const float4*>(nr + 12);
        p4 = *reinterpret_cast<const float4*>(nr + 16);

        float lg[20];
        lg[0]=lgf(g,c0.x); lg[1]=lgf(g,c0.y); lg[2]=lgf(g,c0.z); lg[3]=lgf(g,c0.w);
        lg[4]=lgf(g,c1.x); lg[5]=lgf(g,c1.y); lg[6]=lgf(g,c1.z); lg[7]=lgf(g,c1.w);
        lg[8]=lgf(g,c2.x); lg[9]=lgf(g,c2.y); lg[10]=lgf(g,c2.z); lg[11]=lgf(g,c2.w);
        lg[12]=lgf(g,c3.x); lg[13]=lgf(g,c3.y); lg[14]=lgf(g,c3.z); lg[15]=lgf(g,c3.w);
        lg[16]=lgf(g,c4.x); lg[17]=lgf(g,c4.y); lg[18]=lgf(g,c4.z); lg[19]=lgf(g,c4.w);

        // L[k] = x_log[t0-2+k] with zero padding outside [0,TT)
        float L[20];
        if (s == 0) {
            #pragma unroll
            for (int k = 0; k < 20; ++k) L[k] = lg[k];
        } else if (s < 0) {            // left edge: t0 == 0
            L[0] = 0.f; L[1] = 0.f;
            #pragma unroll
            for (int k = 2; k < 20; ++k) L[k] = lg[k - 2];
        } else {                       // right edge: t0 == TT-16
            #pragma unroll
            for (int k = 0; k < 18; ++k) L[k] = lg[k + 2];
            L[18] = 0.f; L[19] = 0.f;
        }

        #pragma unroll
        for (int j = 0; j < 16; ++j) {
            const float d = fmaf(w0, L[j],
                            fmaf(w1, L[j + 1],
                            fmaf(w2, L[j + 2],
                            fmaf(w3, L[j + 3],
                            fmaf(w4, L[j + 4], bias)))));
            acc[j] += (d >= 0.f) ? d : 0.f;    // lrelu, A_LRELU = 0
        }
    }

    float* __restrict__ po = pool_part + ((size_t)blockIdx.z * (BB * NB) + bc) * TT + t0;
    #pragma unroll
    for (int q = 0; q < 4; ++q)
        *reinterpret_cast<float4*>(po + 4 * q) =
            make_float4(acc[4*q], acc[4*q+1], acc[4*q+2], acc[4*q+3]);
}

// ---------------- Kernel B: sum partials -> (pool - avg11 - avg_b) -> mix -> gauss15 -> ReLU
// grid: 8 batches * 16 tiles of 1024, block 256. Writes unnormalized act and a
// per-(batch,tile) max slot (every slot written -> no memset dispatch needed).
__global__ __launch_bounds__(256) void smooth_kernel(
    const float* __restrict__ pool_part, // [FSPLIT][64][16384]
    const float* __restrict__ avg_w,    // [8,1,11] flat
    const float* __restrict__ avg_b,    // [8]
    const float* __restrict__ mix_w,    // [1,8] flat
    const float* __restrict__ gauss_w,  // [15]
    const float* __restrict__ gauss_b,  // [1]
    float* __restrict__ out,            // [8,16384] (unnormalized act)
    float* __restrict__ pmax)           // [8*16] per-(batch,tile) maxes
{
    __shared__ float sp[NB][1024 + 24]; // pool tile, halo 12 each side (avg±5 then gauss±7)
    __shared__ float sm[1024 + 14];     // x_mix tile, halo 7 each side
    __shared__ float wmax[4];           // per-wave maxes

    const int b  = blockIdx.x >> 4;
    const int t0 = (blockIdx.x & 15) * 1024;

    for (int i = threadIdx.x; i < 1024 + 24; i += 256) {
        const int t = t0 + i - 12;
        const bool in = ((unsigned)t < (unsigned)TT);
        const int tc = in ? t : (t < 0 ? 0 : TT - 1);   // clamped: address always valid
        #pragma unroll
        for (int c = 0; c < NB; ++c) {
            const size_t off = ((size_t)b * NB + c) * TT + tc;
            float s = 0.f;
            #pragma unroll
            for (int z = 0; z < FSPLIT; ++z)
                s += pool_part[(size_t)z * (BB * NB) * TT + off];
            sp[c][i] = in ? s : 0.f;    // zero-pad semantics preserved
        }
    }
    __syncthreads();

    // x_mix[t] = sum_c mix_w[c] * (pool_c[t] - sum_j avg_w[c,j]*pool_c[t+j-5] - avg_b[c])
    for (int i = threadIdx.x; i < 1024 + 14; i += 256) {
        const int t = t0 + i - 7;
        float v = 0.f;
        if ((unsigned)t < (unsigned)TT) {     // gauss zero-pads x_mix
            #pragma unroll
            for (int c = 0; c < NB; ++c) {
                float av = 0.f;
                #pragma unroll
                for (int j = 0; j < 11; ++j)
                    av = fmaf(avg_w[c * 11 + j], sp[c][i + j], av);
                const float e = sp[c][i + 5] - av - avg_b[c];
                v = fmaf(mix_w[c], e, v);
            }
        }
        sm[i] = v;
    }
    __syncthreads();

    const float gb = gauss_b[0];
    float lmax = 0.f;
    for (int i = threadIdx.x; i < 1024; i += 256) {
        float gs = gb;
        #pragma unroll
        for (int k = 0; k < 15; ++k)
            gs = fmaf(gauss_w[k], sm[i + k], gs);
        const float a = (gs >= 0.f) ? gs : 0.f;   // lrelu, A_LRELU = 0
        out[(size_t)b * TT + t0 + i] = a;
        lmax = fmaxf(lmax, a);
    }
    #pragma unroll
    for (int off = 32; off > 0; off >>= 1)
        lmax = fmaxf(lmax, __shfl_down(lmax, off, 64));
    if ((threadIdx.x & 63) == 0) wmax[threadIdx.x >> 6] = lmax;
    __syncthreads();
    if (threadIdx.x == 0)
        pmax[blockIdx.x] = fmaxf(fmaxf(wmax[0], wmax[1]), fmaxf(wmax[2], wmax[3]));
}

// ---------------- Kernel C: reduce 16 tile-maxes per batch, divide by (max + eps)
__global__ __launch_bounds__(256) void norm_kernel(
    float* __restrict__ out, const float* __restrict__ pmax)
{
    const int i = blockIdx.x * 256 + threadIdx.x;   // grid sized exactly B*T/256
    const int b = i >> 14;                          // T = 16384; block-uniform
    const float* __restrict__ pm = pmax + b * 16;
    float m = 0.f;
    #pragma unroll
    for (int k = 0; k < 16; ++k) m = fmaxf(m, pm[k]);
    out[i] = out[i] / (m + 1e-8f);
}

extern "C" void kernel_launch(void* const* d_in, const int* in_sizes, int n_in,
                              void* d_out, int out_size, void* d_ws, size_t ws_size,
                              hipStream_t stream) {
    const float* x        = (const float*)d_in[0];
    const float* log_g    = (const float*)d_in[1];
    const float* diff_w   = (const float*)d_in[2];
    const float* diff_b   = (const float*)d_in[3];
    const float* avg_w    = (const float*)d_in[4];
    const float* avg_b    = (const float*)d_in[5];
    const float* mix_w    = (const float*)d_in[6];
    const float* gauss_w  = (const float*)d_in[7];
    const float* gauss_b  = (const float*)d_in[8];
    float* out = (float*)d_out;

    // workspace: pool_part [8][64][16384] f32 (32 MiB), then 128 floats of tile maxes
    float* pool_part = (float*)d_ws;
    float* pmax = (float*)((char*)d_ws + (size_t)FSPLIT * BB * NB * TT * sizeof(float));

    pool_kernel<<<dim3(BB * NB, TT / 4096, FSPLIT), 256, 0, stream>>>(
        x, log_g, diff_w, diff_b, pool_part);
    smooth_kernel<<<BB * (TT / 1024), 256, 0, stream>>>(pool_part, avg_w, avg_b, mix_w,
                                                        gauss_w, gauss_b, out, pmax);
    norm_kernel<<<(BB * TT) / 256, 256, 0, stream>>>(out, pmax);
}

// Round 12
// 387.103 us; speedup vs baseline: 1.0163x; 1.0163x over previous
//
#include <hip/hip_runtime.h>

// Shapes fixed by the reference setup_inputs():
//   x: [B=8, F=512, T=16384] f32 ; out: [8, 16384] f32
#define TT 16384
#define BB 8
#define NB 8       // N_BANDS
#define FB 64      // F / N_BANDS
#define FSPLIT 4   // freq split (grid = 64*8*4 = 2048 blocks = max residency)
#define FCHUNK (FB / FSPLIT)   // 16 rows per block
#define TSM 256    // smooth time-tile (8*64 = 512 blocks)

__device__ __forceinline__ float lgf(float g, float x) {
    // log1p(g*x) with g*x in [0,10): 1+g*x in [1,11) -> fast hw log is safe.
    return __logf(fmaf(g, x, 1.0f));
}

// ---------------- Kernel A: log-gamma + depthwise 5-tap diff + ReLU + freq-pool
// 8 outputs/thread via an overlapped 12-float register window: 3 float4 loads
// per row cover [t0-2, t0+10) (neighbor overlap hits the same cache lines ->
// no extra lines fetched). No LDS, no shuffles. Edge zero-pad via per-thread
// shift s in {-2,0,+2} (divergent only in the 2 edge waves). Depth-1 prefetch.
__global__ __launch_bounds__(256) void pool_kernel(
    const float* __restrict__ x,
    const float* __restrict__ log_gamma,
    const float* __restrict__ diff_w,   // [8,1,1,5] flat
    const float* __restrict__ diff_b,   // [8]
    float* __restrict__ pool_part)      // [FSPLIT][64][16384]
{
    const int bc = blockIdx.x;                 // b*8 + c
    const int c  = bc & 7;
    const int t0 = blockIdx.y * 2048 + threadIdx.x * 8;
    const int f0 = blockIdx.z * FCHUNK;
    const float* __restrict__ xb = x + ((size_t)bc * FB + f0) * TT;

    const float g  = __expf(log_gamma[c]);
    const float w0 = diff_w[c * 5 + 0], w1 = diff_w[c * 5 + 1],
                w2 = diff_w[c * 5 + 2], w3 = diff_w[c * 5 + 3],
                w4 = diff_w[c * 5 + 4];
    const float bias = diff_b[c];

    // clamped window base: loads always span [b, b+12) within [0, TT]
    const int b = min(max(t0 - 2, 0), TT - 12);
    const int s = t0 - 2 - b;                  // -2 (left edge), 0, +2 (right edge)
    const float* __restrict__ xr = xb + b;

    float acc[8] = {0.f,0.f,0.f,0.f,0.f,0.f,0.f,0.f};

    // prime: row 0's 3 loads
    float4 p0 = *reinterpret_cast<const float4*>(xr);
    float4 p1 = *reinterpret_cast<const float4*>(xr + 4);
    float4 p2 = *reinterpret_cast<const float4*>(xr + 8);

    #pragma unroll 4
    for (int f = 0; f < FCHUNK; ++f) {
        const float4 c0 = p0, c1 = p1, c2 = p2;
        // prefetch next row (clamped to last row; stays in-bounds)
        const float* __restrict__ nr = xr + (size_t)((f + 1 < FCHUNK) ? f + 1 : f) * TT;
        p0 = *reinterpret_cast<const float4*>(nr);
        p1 = *reinterpret_cast<const float4*>(nr + 4);
        p2 = *reinterpret_cast<const float4*>(nr + 8);

        float lg[12];
        lg[0]=lgf(g,c0.x); lg[1]=lgf(g,c0.y); lg[2] =lgf(g,c0.z); lg[3] =lgf(g,c0.w);
        lg[4]=lgf(g,c1.x); lg[5]=lgf(g,c1.y); lg[6] =lgf(g,c1.z); lg[7] =lgf(g,c1.w);
        lg[8]=lgf(g,c2.x); lg[9]=lgf(g,c2.y); lg[10]=lgf(g,c2.z); lg[11]=lgf(g,c2.w);

        // L[k] = x_log[t0-2+k] with zero padding outside [0,TT)
        float L[12];
        if (s == 0) {
            #pragma unroll
            for (int k = 0; k < 12; ++k) L[k] = lg[k];
        } else if (s < 0) {            // left edge: t0 == 0
            L[0] = 0.f; L[1] = 0.f;
            #pragma unroll
            for (int k = 2; k < 12; ++k) L[k] = lg[k - 2];
        } else {                       // right edge: t0 == TT-8
            #pragma unroll
            for (int k = 0; k < 10; ++k) L[k] = lg[k + 2];
            L[10] = 0.f; L[11] = 0.f;
        }

        #pragma unroll
        for (int j = 0; j < 8; ++j) {
            const float d = fmaf(w0, L[j],
                            fmaf(w1, L[j + 1],
                            fmaf(w2, L[j + 2],
                            fmaf(w3, L[j + 3],
                            fmaf(w4, L[j + 4], bias)))));
            acc[j] += (d >= 0.f) ? d : 0.f;    // lrelu, A_LRELU = 0
        }
    }

    float* __restrict__ po = pool_part + ((size_t)blockIdx.z * (BB * NB) + bc) * TT + t0;
    *reinterpret_cast<float4*>(po)     = make_float4(acc[0], acc[1], acc[2], acc[3]);
    *reinterpret_cast<float4*>(po + 4) = make_float4(acc[4], acc[5], acc[6], acc[7]);
}

// ---------------- Kernel B: sum partials -> (pool - avg11 - avg_b) -> mix -> gauss15 -> ReLU
// grid: 8 batches * 64 tiles of 256 = 512 blocks (2 per CU; was 128 -> half the
// machine idle and long serial phases). Writes unnormalized act + per-tile max.
__global__ __launch_bounds__(256) void smooth_kernel(
    const float* __restrict__ pool_part, // [FSPLIT][64][16384]
    const float* __restrict__ avg_w,    // [8,1,11] flat
    const float* __restrict__ avg_b,    // [8]
    const float* __restrict__ mix_w,    // [1,8] flat
    const float* __restrict__ gauss_w,  // [15]
    const float* __restrict__ gauss_b,  // [1]
    float* __restrict__ out,            // [8,16384] (unnormalized act)
    float* __restrict__ pmax)           // [8*64] per-(batch,tile) maxes
{
    __shared__ float sp[NB][TSM + 24];  // pool tile, halo 12 each side (avg±5, gauss±7)
    __shared__ float sm[TSM + 14];      // x_mix tile, halo 7 each side
    __shared__ float wmax[4];           // per-wave maxes

    const int b  = blockIdx.x >> 6;     // 64 tiles per batch
    const int t0 = (blockIdx.x & 63) * TSM;

    for (int i = threadIdx.x; i < TSM + 24; i += 256) {
        const int t = t0 + i - 12;
        const bool in = ((unsigned)t < (unsigned)TT);
        const int tc = in ? t : (t < 0 ? 0 : TT - 1);   // clamped: address always valid
        #pragma unroll
        for (int c = 0; c < NB; ++c) {
            const size_t off = ((size_t)b * NB + c) * TT + tc;
            float s = 0.f;
            #pragma unroll
            for (int z = 0; z < FSPLIT; ++z)
                s += pool_part[(size_t)z * (BB * NB) * TT + off];
            sp[c][i] = in ? s : 0.f;    // zero-pad semantics preserved
        }
    }
    __syncthreads();

    // x_mix[t] = sum_c mix_w[c] * (pool_c[t] - sum_j avg_w[c,j]*pool_c[t+j-5] - avg_b[c])
    for (int i = threadIdx.x; i < TSM + 14; i += 256) {
        const int t = t0 + i - 7;
        float v = 0.f;
        if ((unsigned)t < (unsigned)TT) {     // gauss zero-pads x_mix
            #pragma unroll
            for (int c = 0; c < NB; ++c) {
                float av = 0.f;
                #pragma unroll
                for (int j = 0; j < 11; ++j)
                    av = fmaf(avg_w[c * 11 + j], sp[c][i + j], av);
                const float e = sp[c][i + 5] - av - avg_b[c];
                v = fmaf(mix_w[c], e, v);
            }
        }
        sm[i] = v;
    }
    __syncthreads();

    // exactly one output per thread (TSM == 256)
    const int i = threadIdx.x;
    float gs = gauss_b[0];
    #pragma unroll
    for (int k = 0; k < 15; ++k)
        gs = fmaf(gauss_w[k], sm[i + k], gs);
    const float a = (gs >= 0.f) ? gs : 0.f;   // lrelu, A_LRELU = 0
    out[(size_t)b * TT + t0 + i] = a;

    float lmax = a;
    #pragma unroll
    for (int off = 32; off > 0; off >>= 1)
        lmax = fmaxf(lmax, __shfl_down(lmax, off, 64));
    if ((threadIdx.x & 63) == 0) wmax[threadIdx.x >> 6] = lmax;
    __syncthreads();
    if (threadIdx.x == 0)
        pmax[blockIdx.x] = fmaxf(fmaxf(wmax[0], wmax[1]), fmaxf(wmax[2], wmax[3]));
}

// ---------------- Kernel C: reduce 64 tile-maxes per batch, divide by (max + eps)
__global__ __launch_bounds__(256) void norm_kernel(
    float* __restrict__ out, const float* __restrict__ pmax)
{
    const int i = blockIdx.x * 256 + threadIdx.x;   // grid sized exactly B*T/256
    const int b = i >> 14;                          // T = 16384; block-uniform
    const float* __restrict__ pm = pmax + b * 64;   // uniform -> scalar loads
    float m = 0.f;
    #pragma unroll
    for (int k = 0; k < 64; ++k) m = fmaxf(m, pm[k]);
    out[i] = out[i] / (m + 1e-8f);
}

extern "C" void kernel_launch(void* const* d_in, const int* in_sizes, int n_in,
                              void* d_out, int out_size, void* d_ws, size_t ws_size,
                              hipStream_t stream) {
    const float* x        = (const float*)d_in[0];
    const float* log_g    = (const float*)d_in[1];
    const float* diff_w   = (const float*)d_in[2];
    const float* diff_b   = (const float*)d_in[3];
    const float* avg_w    = (const float*)d_in[4];
    const float* avg_b    = (const float*)d_in[5];
    const float* mix_w    = (const float*)d_in[6];
    const float* gauss_w  = (const float*)d_in[7];
    const float* gauss_b  = (const float*)d_in[8];
    float* out = (float*)d_out;

    // workspace: pool_part [4][64][16384] f32 (16 MiB), then 512 floats of tile maxes
    float* pool_part = (float*)d_ws;
    float* pmax = (float*)((char*)d_ws + (size_t)FSPLIT * BB * NB * TT * sizeof(float));

    pool_kernel<<<dim3(BB * NB, TT / 2048, FSPLIT), 256, 0, stream>>>(
        x, log_g, diff_w, diff_b, pool_part);
    smooth_kernel<<<BB * (TT / TSM), 256, 0, stream>>>(pool_part, avg_w, avg_b, mix_w,
                                                       gauss_w, gauss_b, out, pmax);
    norm_kernel<<<(BB * TT) / 256, 256, 0, stream>>>(out, pmax);
}